// Round 1
// baseline (2269.041 us; speedup 1.0000x reference)
//
#include <hip/hip_runtime.h>

#define NPTS   120000
#define NOFF   28      // 27 neighbor offsets + 1 point-transform slot
#define CHUNKS 7       // 448 / 64
#define NSTEP  (NOFF * CHUNKS)   // 196 K-steps of 64

typedef __bf16 bf16;
typedef __bf16 bf16x8 __attribute__((ext_vector_type(8)));
typedef float  f32x4  __attribute__((ext_vector_type(4)));

// ---------------- weight prep: pack (Wz|Wr) -> WB1 [koff][chunk][kseg][n(256)][8k] bf16
__global__ void wprep1(const float* __restrict__ Wz, const float* __restrict__ Wzp,
                       const float* __restrict__ Wr, const float* __restrict__ Wrp,
                       bf16* __restrict__ WB1)
{
    int bid  = blockIdx.x;          // 28*7*8 = 1568
    int koff = bid / 56;
    int rem  = bid % 56;
    int ch   = rem / 8;
    int kseg = rem % 8;
    int n    = threadIdx.x;         // 256
    int cinb = ch * 64 + kseg * 8;
    bf16x8 v;
    if (n < 128) {
        int col = n;
        #pragma unroll
        for (int j = 0; j < 8; ++j) {
            int cin = cinb + j;
            float w = (koff < 27) ? Wz[((long)koff * 448 + cin) * 128 + col]
                                  : Wzp[(long)cin * 128 + col];
            v[j] = (bf16)w;
        }
    } else {
        int col = n - 128;
        #pragma unroll
        for (int j = 0; j < 8; ++j) {
            int cin = cinb + j;
            float w = (koff < 27) ? Wr[((long)koff * 448 + cin) * 128 + col]
                                  : Wrp[(long)cin * 128 + col];
            v[j] = (bf16)w;
        }
    }
    *(bf16x8*)(WB1 + ((long)bid * 256 + n) * 8) = v;
}

// ---------------- weight prep: pack Wq -> WB2 [koff][chunk][kseg][n(128)][8k] bf16
__global__ void wprep2(const float* __restrict__ Wq, const float* __restrict__ Wqp,
                       bf16* __restrict__ WB2)
{
    int bid  = blockIdx.x;          // 1568
    int koff = bid / 56;
    int rem  = bid % 56;
    int ch   = rem / 8;
    int kseg = rem % 8;
    int n    = threadIdx.x;         // 128
    int cinb = ch * 64 + kseg * 8;
    bf16x8 v;
    #pragma unroll
    for (int j = 0; j < 8; ++j) {
        int cin = cinb + j;
        float w = (koff < 27) ? Wq[((long)koff * 448 + cin) * 128 + n]
                              : Wqp[(long)cin * 128 + n];
        v[j] = (bf16)w;
    }
    *(bf16x8*)(WB2 + ((long)bid * 128 + n) * 8) = v;
}

// ---------------- feature prep: F1 = bf16([h|x]), vectorized 8 cols/thread
__global__ void fprep(const float* __restrict__ h, const float* __restrict__ x,
                      bf16* __restrict__ F1)
{
    long g = (long)blockIdx.x * blockDim.x + threadIdx.x;
    if (g >= (long)NPTS * 56) return;       // 448/8 = 56 groups per row
    int p = (int)(g / 56);
    int c = (int)(g % 56) * 8;              // 128 divisible by 8 -> no h/x straddle
    const float* src = (c < 128) ? h + (long)p * 128 + c
                                 : x + (long)p * 320 + (c - 128);
    float4 a = ((const float4*)src)[0];
    float4 b = ((const float4*)src)[1];
    bf16x8 v;
    v[0] = (bf16)a.x; v[1] = (bf16)a.y; v[2] = (bf16)a.z; v[3] = (bf16)a.w;
    v[4] = (bf16)b.x; v[5] = (bf16)b.y; v[6] = (bf16)b.z; v[7] = (bf16)b.w;
    *(bf16x8*)(F1 + (long)p * 448 + c) = v;
}

// ---------------- pipelined gather-GEMM, MROWS x NCOLS tile, 512 threads (8 waves, 64x64 each)
// Software pipeline (T3+T4): STG-deep LDS ring, counted vmcnt, raw s_barrier (no
// compiler vmcnt(0) drain).  Gather indices preloaded once into an LDS table so
// per-step index reads are lgkmcnt traffic, never touching the vmcnt queue.
// GATE==1 (128x256, STG=3): cols 0..127 -> z=sigmoid -> zbuf(fp32); cols 128..255 -> r,
//                    f2[p*128+cc] = bf16(r*h).
// GATE==2 (256x128, STG=2): A chunks 0-1 from f2 (r*h), chunks 2-6 from F (x part);
//                    q=tanh, out=(1-z)h+zq.
template<int MROWS, int NCOLS, int GATE>
__global__ __launch_bounds__(512)
void gconv(const bf16* __restrict__ F, const int* __restrict__ nbr,
           const bf16* __restrict__ WB, const float* __restrict__ b0,
           const float* __restrict__ b1, const float* __restrict__ hbuf,
           float* __restrict__ zbuf, bf16* __restrict__ f2,
           float* __restrict__ out, const bf16* __restrict__ zrow)
{
    constexpr int THREADS = 512;
    constexpr int MW  = MROWS / 64;             // m-waves
    constexpr int AP  = 8 * MROWS / THREADS;    // A-tile 16B units per thread
    constexpr int BP  = 8 * NCOLS / THREADS;    // B-tile 16B units per thread
    constexpr int STG = (GATE == 1) ? 3 : 2;    // pipeline depth (LDS ring stages)
    constexpr int ASZ = 8 * MROWS * 8;          // bf16 elems per A stage
    constexpr int BSZ = 8 * NCOLS * 8;          // bf16 elems per B stage
    constexpr int LPB = AP + BP;                // global_load_lds per wave per stage (=6)

    __shared__ __align__(16) bf16 lA[STG * ASZ];
    __shared__ __align__(16) bf16 lB[STG * BSZ];
    __shared__ int lidx[NOFF * MROWS];          // all 28 gather indices per row

    const int t    = threadIdx.x;
    const int lane = t & 63;
    const int w    = t >> 6;
    const int m0   = (w % MW) * 64;
    const int n0   = (w / MW) * 64;
    const int base = blockIdx.x * MROWS;
    const int ar   = t % MROWS;          // A row this thread stages
    const int aks0 = t / MROWS;

    // ---- preload the full per-block gather-index table (one-time; L2/L3 hits)
    for (int i = t; i < NOFF * MROWS; i += THREADS) {
        int k = i / MROWS, r = i - k * MROWS;
        int p = base + r;
        int idx = -1;
        if (p < NPTS) idx = (k == 27) ? p : nbr[(long)p * 27 + k];
        lidx[i] = idx;
    }
    __syncthreads();

    f32x4 acc[4][4];
    #pragma unroll
    for (int i = 0; i < 4; ++i)
        #pragma unroll
        for (int j = 0; j < 4; ++j)
            acc[i][j] = {0.f, 0.f, 0.f, 0.f};

    // ---- stage step s into ring slot s%STG (6 global_load_lds per wave)
    auto stage = [&](int s) {
        const int koff = s / CHUNKS;
        const int ch   = s - koff * CHUNKS;
        const int bsl  = s % STG;
        const int idx  = lidx[koff * MROWS + ar];   // ds_read: lgkmcnt only
        const bf16* asrc;
        if constexpr (GATE == 2) {
            asrc = (idx < 0) ? zrow
                 : (ch < 2)  ? f2 + (long)idx * 128 + ch * 64
                             : F  + (long)idx * 448 + ch * 64;
        } else {
            asrc = (idx < 0) ? zrow : F + (long)idx * 448 + ch * 64;
        }
        bf16* la = lA + bsl * ASZ;
        #pragma unroll
        for (int p = 0; p < AP; ++p) {
            int kseg = aks0 + p * (THREADS / MROWS);
            __builtin_amdgcn_global_load_lds(
                (void*)(asrc + kseg * 8),
                (void*)(la + ((long)t + (long)p * THREADS) * 8), 16, 0, 0);
        }
        const bf16* bsrc = WB + (long)s * (NCOLS * 64);
        bf16* lb = lB + bsl * BSZ;
        #pragma unroll
        for (int p = 0; p < BP; ++p) {
            __builtin_amdgcn_global_load_lds(
                (void*)(bsrc + ((long)t + (long)p * THREADS) * 8),
                (void*)(lb + ((long)t + (long)p * THREADS) * 8), 16, 0, 0);
        }
    };

    // ---- prologue: fill STG-1 ring slots
    #pragma unroll
    for (int s = 0; s < STG - 1; ++s) stage(s);

    // ---- main loop: one K-step (BK=64) per iteration, 2 barriers, counted vmcnt
    for (int s = 0; s < NSTEP; ++s) {
        if (s + STG - 1 < NSTEP) stage(s + STG - 1);   // prefetch into slot just freed

        // wait until batch(s) has landed: allow min(STG-1, NSTEP-1-s) newer batches
        if constexpr (STG == 3) {
            if (s + 2 < NSTEP)      asm volatile("s_waitcnt vmcnt(%0)" :: "i"(2 * LPB) : "memory");
            else if (s + 1 < NSTEP) asm volatile("s_waitcnt vmcnt(%0)" :: "i"(LPB) : "memory");
            else                    asm volatile("s_waitcnt vmcnt(0)" ::: "memory");
        } else {
            if (s + 1 < NSTEP)      asm volatile("s_waitcnt vmcnt(%0)" :: "i"(LPB) : "memory");
            else                    asm volatile("s_waitcnt vmcnt(0)" ::: "memory");
        }
        __builtin_amdgcn_s_barrier();          // all waves' batch(s) now visible in LDS
        __builtin_amdgcn_sched_barrier(0);     // rule #18: no hoisting past the wait cluster

        const bf16x8* lAv = (const bf16x8*)(lA + (s % STG) * ASZ);
        const bf16x8* lBv = (const bf16x8*)(lB + (s % STG) * BSZ);
        #pragma unroll
        for (int kk = 0; kk < 2; ++kk) {
            const int aseg = kk * 4 + (lane >> 4);
            bf16x8 af[4], bfr[4];
            #pragma unroll
            for (int mi = 0; mi < 4; ++mi)
                af[mi] = lAv[aseg * MROWS + m0 + mi * 16 + (lane & 15)];
            #pragma unroll
            for (int ni = 0; ni < 4; ++ni)
                bfr[ni] = lBv[aseg * NCOLS + n0 + ni * 16 + (lane & 15)];
            __builtin_amdgcn_s_setprio(1);
            #pragma unroll
            for (int mi = 0; mi < 4; ++mi)
                #pragma unroll
                for (int ni = 0; ni < 4; ++ni)
                    acc[mi][ni] = __builtin_amdgcn_mfma_f32_16x16x32_bf16(
                        af[mi], bfr[ni], acc[mi][ni], 0, 0, 0);
            __builtin_amdgcn_s_setprio(0);
        }
        __builtin_amdgcn_sched_barrier(0);
        __builtin_amdgcn_s_barrier();          // ring-slot rotation: all reads of slot done
    }

    // ---- epilogue: C/D layout col=lane&15, row=(lane>>4)*4+reg  [m89/m91]
    const int quad = lane >> 4;
    const int lc   = lane & 15;
    #pragma unroll
    for (int mi = 0; mi < 4; ++mi) {
        int rb = m0 + mi * 16 + quad * 4;
        #pragma unroll
        for (int ni = 0; ni < 4; ++ni) {
            int c = n0 + ni * 16 + lc;
            f32x4 v = acc[mi][ni];
            #pragma unroll
            for (int rg = 0; rg < 4; ++rg) {
                int p = base + rb + rg;
                if (p < NPTS) {
                    float pre = v[rg];
                    if constexpr (GATE == 1) {
                        if (c < 128) {
                            float z = 1.f / (1.f + __expf(-(pre + b0[c])));
                            zbuf[(long)p * 128 + c] = z;
                        } else {
                            int cc = c - 128;
                            float r = 1.f / (1.f + __expf(-(pre + b1[cc])));
                            f2[(long)p * 128 + cc] = (bf16)(r * hbuf[(long)p * 128 + cc]);
                        }
                    } else {
                        float q  = tanhf(pre + b0[c]);
                        float z  = zbuf[(long)p * 128 + c];
                        float hv = hbuf[(long)p * 128 + c];
                        out[(long)p * 128 + c] = (1.f - z) * hv + z * q;
                    }
                }
            }
        }
    }
}

extern "C" void kernel_launch(void* const* d_in, const int* in_sizes, int n_in,
                              void* d_out, int out_size, void* d_ws, size_t ws_size,
                              hipStream_t stream)
{
    const float* h   = (const float*)d_in[0];
    const float* x   = (const float*)d_in[1];
    const int*   nbr = (const int*)d_in[2];
    const float* Wz  = (const float*)d_in[3];
    const float* Wzp = (const float*)d_in[4];
    const float* bz  = (const float*)d_in[5];
    const float* Wr  = (const float*)d_in[6];
    const float* Wrp = (const float*)d_in[7];
    const float* br  = (const float*)d_in[8];
    const float* Wq  = (const float*)d_in[9];
    const float* Wqp = (const float*)d_in[10];
    const float* bq  = (const float*)d_in[11];
    float* out = (float*)d_out;

    char* ws = (char*)d_ws;
    bf16* WB1 = (bf16*)ws;  ws += (size_t)1568 * 256 * 8 * 2;   // 6.42 MB
    bf16* WB2 = (bf16*)ws;  ws += (size_t)1568 * 128 * 8 * 2;   // 3.21 MB
    bf16* F1  = (bf16*)ws;  ws += (size_t)NPTS * 448 * 2;       // 107.5 MB
    bf16* F2  = (bf16*)ws;  ws += (size_t)NPTS * 128 * 2;       // 30.7 MB  (r*h only)
    bf16* zrow = (bf16*)ws; ws += 1024;                          // zero row for masked gathers
    float* zbuf = out;  // z gate stored in d_out (fp32), overwritten by pass 2

    hipMemsetAsync(zrow, 0, 1024, stream);
    wprep1<<<1568, 256, 0, stream>>>(Wz, Wzp, Wr, Wrp, WB1);
    wprep2<<<1568, 128, 0, stream>>>(Wq, Wqp, WB2);
    long groups = (long)NPTS * 56;
    fprep<<<(int)((groups + 255) / 256), 256, 0, stream>>>(h, x, F1);

    gconv<128, 256, 1><<<(NPTS + 127) / 128, 512, 0, stream>>>(
        F1, nbr, WB1, bz, br, h, zbuf, F2, nullptr, zrow);
    gconv<256, 128, 2><<<(NPTS + 255) / 256, 512, 0, stream>>>(
        F1, nbr, WB2, bq, nullptr, h, zbuf, F2, out, zrow);
}

// Round 2
// 1735.356 us; speedup vs baseline: 1.3075x; 1.3075x over previous
//
#include <hip/hip_runtime.h>

#define NPTS   120000
#define NOFF   28      // 27 neighbor offsets + 1 point-transform slot
#define CHUNKS 7       // 448 / 64
#define NSTEP  (NOFF * CHUNKS)   // 196 K-steps of 64

typedef __bf16 bf16;
typedef __bf16 bf16x8 __attribute__((ext_vector_type(8)));
typedef float  f32x4  __attribute__((ext_vector_type(4)));

// ---------------- weight prep: pack (Wz|Wr) -> WB1 [koff][chunk][kseg][n(256)][8k] bf16
__global__ void wprep1(const float* __restrict__ Wz, const float* __restrict__ Wzp,
                       const float* __restrict__ Wr, const float* __restrict__ Wrp,
                       bf16* __restrict__ WB1)
{
    int bid  = blockIdx.x;          // 28*7*8 = 1568
    int koff = bid / 56;
    int rem  = bid % 56;
    int ch   = rem / 8;
    int kseg = rem % 8;
    int n    = threadIdx.x;         // 256
    int cinb = ch * 64 + kseg * 8;
    bf16x8 v;
    if (n < 128) {
        int col = n;
        #pragma unroll
        for (int j = 0; j < 8; ++j) {
            int cin = cinb + j;
            float w = (koff < 27) ? Wz[((long)koff * 448 + cin) * 128 + col]
                                  : Wzp[(long)cin * 128 + col];
            v[j] = (bf16)w;
        }
    } else {
        int col = n - 128;
        #pragma unroll
        for (int j = 0; j < 8; ++j) {
            int cin = cinb + j;
            float w = (koff < 27) ? Wr[((long)koff * 448 + cin) * 128 + col]
                                  : Wrp[(long)cin * 128 + col];
            v[j] = (bf16)w;
        }
    }
    *(bf16x8*)(WB1 + ((long)bid * 256 + n) * 8) = v;
}

// ---------------- weight prep: pack Wq -> WB2 [koff][chunk][kseg][n(128)][8k] bf16
__global__ void wprep2(const float* __restrict__ Wq, const float* __restrict__ Wqp,
                       bf16* __restrict__ WB2)
{
    int bid  = blockIdx.x;          // 1568
    int koff = bid / 56;
    int rem  = bid % 56;
    int ch   = rem / 8;
    int kseg = rem % 8;
    int n    = threadIdx.x;         // 128
    int cinb = ch * 64 + kseg * 8;
    bf16x8 v;
    #pragma unroll
    for (int j = 0; j < 8; ++j) {
        int cin = cinb + j;
        float w = (koff < 27) ? Wq[((long)koff * 448 + cin) * 128 + n]
                              : Wqp[(long)cin * 128 + n];
        v[j] = (bf16)w;
    }
    *(bf16x8*)(WB2 + ((long)bid * 128 + n) * 8) = v;
}

// ---------------- feature prep: F1 = bf16([h|x]), vectorized 8 cols/thread
__global__ void fprep(const float* __restrict__ h, const float* __restrict__ x,
                      bf16* __restrict__ F1)
{
    long g = (long)blockIdx.x * blockDim.x + threadIdx.x;
    if (g >= (long)NPTS * 56) return;       // 448/8 = 56 groups per row
    int p = (int)(g / 56);
    int c = (int)(g % 56) * 8;              // 128 divisible by 8 -> no h/x straddle
    const float* src = (c < 128) ? h + (long)p * 128 + c
                                 : x + (long)p * 320 + (c - 128);
    float4 a = ((const float4*)src)[0];
    float4 b = ((const float4*)src)[1];
    bf16x8 v;
    v[0] = (bf16)a.x; v[1] = (bf16)a.y; v[2] = (bf16)a.z; v[3] = (bf16)a.w;
    v[4] = (bf16)b.x; v[5] = (bf16)b.y; v[6] = (bf16)b.z; v[7] = (bf16)b.w;
    *(bf16x8*)(F1 + (long)p * 448 + c) = v;
}

// ---------------- PASS 1: 256x256 4-phase pipelined gather-GEMM (m201-template port)
// 512 threads = 8 waves, per-wave 128x64 output, 64 MFMA per K-step in 4 phases of 16.
// 2-slot LDS dbuf; prefetch for step s+1 issued 2 ops/phase during step s; counted
// vmcnt(4) at the two half-K boundaries (never drains to 0 mid-loop).
__global__ __launch_bounds__(512, 2)
void gconv1p(const bf16* __restrict__ F, const int* __restrict__ nbr,
             const bf16* __restrict__ WB, const float* __restrict__ b0,
             const float* __restrict__ b1, const float* __restrict__ hbuf,
             float* __restrict__ zbuf, bf16* __restrict__ f2,
             const bf16* __restrict__ zrow)
{
    constexpr int BM = 256, BN = 256;
    constexpr int ASZ = 8 * BM * 8;     // 16384 bf16 = 32 KB per slot
    constexpr int BSZ = 8 * BN * 8;     // 32 KB per slot

    __shared__ __align__(16) bf16 lA[2 * ASZ];   // 64 KB
    __shared__ __align__(16) bf16 lB[2 * BSZ];   // 64 KB
    __shared__ int lidx[NOFF * BM];              // 28 KB gather-index table

    const int t    = threadIdx.x;
    const int lane = t & 63;
    const int w    = t >> 6;
    const int m0   = (w & 1) * 128;     // wave row block (2 m-groups)
    const int n0   = (w >> 1) * 64;     // wave col block (4 n-groups)
    const int base = blockIdx.x * BM;
    const int ar   = t & 255;           // A row this thread stages
    const int aks0 = t >> 8;            // 0 or 1

    // ---- one-time: preload all 28 gather indices per row (global loads, pre-pipeline)
    for (int i = t; i < NOFF * BM; i += 512) {
        int k = i >> 8, r = i & 255;
        int p = base + r;
        int idx = -1;
        if (p < NPTS) idx = (k == 27) ? p : nbr[(long)p * 27 + k];
        lidx[i] = idx;
    }
    __syncthreads();

    f32x4 acc[8][4];
    #pragma unroll
    for (int i = 0; i < 8; ++i)
        #pragma unroll
        for (int j = 0; j < 4; ++j)
            acc[i][j] = {0.f, 0.f, 0.f, 0.f};

    // op p covers ksegs {2p, 2p+1}: half 0 = ops 0,1 (ksegs 0-3), half 1 = ops 2,3
    auto issueA = [&](int idx, int ch, int slot, int p) {
        const bf16* asrc = (idx < 0) ? zrow : F + (long)idx * 448 + ch * 64;
        const int kseg = aks0 + 2 * p;
        __builtin_amdgcn_global_load_lds(
            (void*)(asrc + kseg * 8),
            (void*)(lA + slot * ASZ + (((kseg << 8) | ar) * 8)), 16, 0, 0);
    };
    auto issueB = [&](int s, int slot, int p) {
        const bf16* bsrc = WB + (long)s * (BN * 64);
        const int e = t + p * 512;      // element (kseg*256+col); kseg = e>>8 = {2p,2p+1}
        __builtin_amdgcn_global_load_lds(
            (void*)(bsrc + (long)e * 8),
            (void*)(lB + slot * BSZ + (long)e * 8), 16, 0, 0);
    };

    // ---- prologue: fully stage step 0 into slot 0, drain once
    {
        const int idx0 = lidx[ar];      // koff=0
        #pragma unroll
        for (int p = 0; p < 4; ++p) issueA(idx0, 0, 0, p);
        #pragma unroll
        for (int p = 0; p < 4; ++p) issueB(0, 0, p);
        asm volatile("s_waitcnt vmcnt(0)" ::: "memory");
        __syncthreads();
    }

    const bf16x8* lAv = (const bf16x8*)lA;
    const bf16x8* lBv = (const bf16x8*)lB;
    const int lc = lane & 15;
    const int q4 = lane >> 4;

    for (int s = 0; s < NSTEP; ++s) {
        const int slot  = s & 1;
        const int nslot = slot ^ 1;
        const bool pf   = (s + 1 < NSTEP);
        const int koff1 = (s + 1) / CHUNKS;
        const int ch1   = (s + 1) - koff1 * CHUNKS;
        const int nidx  = pf ? lidx[(koff1 << 8) | ar] : 0;   // ds_read, lgkm only

        const int av = slot * (ASZ / 8);
        const int bv = slot * (BSZ / 8);
        const int a0 = q4;        // aseg for kk=0
        const int a1 = 4 + q4;    // aseg for kk=1

        bf16x8 af[4], bfr[4];

        // ======== phase 1: kk=0, mi 0-3 ========
        #pragma unroll
        for (int m = 0; m < 4; ++m) af[m]  = lAv[av + a0 * 256 + m0 + m * 16 + lc];
        #pragma unroll
        for (int n = 0; n < 4; ++n) bfr[n] = lBv[bv + a0 * 256 + n0 + n * 16 + lc];
        if (pf) { issueA(nidx, ch1, nslot, 0); issueB(s + 1, nslot, 0); }
        __builtin_amdgcn_sched_barrier(0);
        __builtin_amdgcn_s_barrier();
        asm volatile("s_waitcnt lgkmcnt(0)" ::: "memory");
        __builtin_amdgcn_sched_barrier(0);
        __builtin_amdgcn_s_setprio(1);
        #pragma unroll
        for (int m = 0; m < 4; ++m)
            #pragma unroll
            for (int n = 0; n < 4; ++n)
                acc[m][n] = __builtin_amdgcn_mfma_f32_16x16x32_bf16(af[m], bfr[n], acc[m][n], 0, 0, 0);
        __builtin_amdgcn_s_setprio(0);
        __builtin_amdgcn_sched_barrier(0);
        __builtin_amdgcn_s_barrier();

        // ======== phase 2: kk=0, mi 4-7 (reuse bfr) ========
        #pragma unroll
        for (int m = 0; m < 4; ++m) af[m] = lAv[av + a0 * 256 + m0 + 64 + m * 16 + lc];
        if (pf) { issueA(nidx, ch1, nslot, 1); issueB(s + 1, nslot, 1); }
        __builtin_amdgcn_sched_barrier(0);
        __builtin_amdgcn_s_barrier();
        asm volatile("s_waitcnt lgkmcnt(0)" ::: "memory");
        __builtin_amdgcn_sched_barrier(0);
        __builtin_amdgcn_s_setprio(1);
        #pragma unroll
        for (int m = 0; m < 4; ++m)
            #pragma unroll
            for (int n = 0; n < 4; ++n)
                acc[4 + m][n] = __builtin_amdgcn_mfma_f32_16x16x32_bf16(af[m], bfr[n], acc[4 + m][n], 0, 0, 0);
        __builtin_amdgcn_s_setprio(0);
        __builtin_amdgcn_sched_barrier(0);
        // half-K boundary: current slot ksegs 4-7 must be landed before phase 3 reads
        if (pf) asm volatile("s_waitcnt vmcnt(4)" ::: "memory");
        else    asm volatile("s_waitcnt vmcnt(0)" ::: "memory");
        __builtin_amdgcn_s_barrier();

        // ======== phase 3: kk=1, mi 0-3 ========
        #pragma unroll
        for (int m = 0; m < 4; ++m) af[m]  = lAv[av + a1 * 256 + m0 + m * 16 + lc];
        #pragma unroll
        for (int n = 0; n < 4; ++n) bfr[n] = lBv[bv + a1 * 256 + n0 + n * 16 + lc];
        if (pf) { issueA(nidx, ch1, nslot, 2); issueB(s + 1, nslot, 2); }
        __builtin_amdgcn_sched_barrier(0);
        __builtin_amdgcn_s_barrier();
        asm volatile("s_waitcnt lgkmcnt(0)" ::: "memory");
        __builtin_amdgcn_sched_barrier(0);
        __builtin_amdgcn_s_setprio(1);
        #pragma unroll
        for (int m = 0; m < 4; ++m)
            #pragma unroll
            for (int n = 0; n < 4; ++n)
                acc[m][n] = __builtin_amdgcn_mfma_f32_16x16x32_bf16(af[m], bfr[n], acc[m][n], 0, 0, 0);
        __builtin_amdgcn_s_setprio(0);
        __builtin_amdgcn_sched_barrier(0);
        __builtin_amdgcn_s_barrier();

        // ======== phase 4: kk=1, mi 4-7 (reuse bfr) ========
        #pragma unroll
        for (int m = 0; m < 4; ++m) af[m] = lAv[av + a1 * 256 + m0 + 64 + m * 16 + lc];
        if (pf) { issueA(nidx, ch1, nslot, 3); issueB(s + 1, nslot, 3); }
        __builtin_amdgcn_sched_barrier(0);
        __builtin_amdgcn_s_barrier();
        asm volatile("s_waitcnt lgkmcnt(0)" ::: "memory");
        __builtin_amdgcn_sched_barrier(0);
        __builtin_amdgcn_s_setprio(1);
        #pragma unroll
        for (int m = 0; m < 4; ++m)
            #pragma unroll
            for (int n = 0; n < 4; ++n)
                acc[4 + m][n] = __builtin_amdgcn_mfma_f32_16x16x32_bf16(af[m], bfr[n], acc[4 + m][n], 0, 0, 0);
        __builtin_amdgcn_s_setprio(0);
        __builtin_amdgcn_sched_barrier(0);
        // K-step boundary: next slot ksegs 0-3 must be landed before next phase-1 reads
        if (pf) asm volatile("s_waitcnt vmcnt(4)" ::: "memory");
        __builtin_amdgcn_s_barrier();
    }

    // ---- epilogue: C/D layout col=lane&15, row=(lane>>4)*4+reg  [m89/m91]
    #pragma unroll
    for (int mi = 0; mi < 8; ++mi) {
        int rb = m0 + mi * 16 + q4 * 4;
        #pragma unroll
        for (int ni = 0; ni < 4; ++ni) {
            int c = n0 + ni * 16 + lc;
            f32x4 v = acc[mi][ni];
            #pragma unroll
            for (int rg = 0; rg < 4; ++rg) {
                int p = base + rb + rg;
                if (p < NPTS) {
                    float pre = v[rg];
                    if (c < 128) {
                        float z = 1.f / (1.f + __expf(-(pre + b0[c])));
                        zbuf[(long)p * 128 + c] = z;
                    } else {
                        int cc = c - 128;
                        float r = 1.f / (1.f + __expf(-(pre + b1[cc])));
                        f2[(long)p * 128 + cc] = (bf16)(r * hbuf[(long)p * 128 + cc]);
                    }
                }
            }
        }
    }
}

// ---------------- PASS 2: round-0 drain-style gather-GEMM (3 blocks/CU, proven)
// GATE==2 (256x128): A chunks 0-1 read from f2 (r*h, 128-wide), chunks 2-6 from F;
//                    q=tanh, out=(1-z)h+zq.
template<int MROWS, int NCOLS, int GATE>
__global__ __launch_bounds__(512)
void gconv(const bf16* __restrict__ F, const int* __restrict__ nbr,
           const bf16* __restrict__ WB, const float* __restrict__ b0,
           const float* __restrict__ b1, const float* __restrict__ hbuf,
           float* __restrict__ zbuf, bf16* __restrict__ f2,
           float* __restrict__ out, const bf16* __restrict__ zrow)
{
    constexpr int THREADS = 512;
    constexpr int MW = MROWS / 64;              // m-waves
    constexpr int AP = 8 * MROWS / THREADS;     // A-tile 16B units per thread
    constexpr int BP = 8 * NCOLS / THREADS;     // B-tile 16B units per thread

    __shared__ __align__(16) bf16 lA[8 * MROWS * 8];    // [kseg][row][8]
    __shared__ __align__(16) bf16 lB[8 * NCOLS * 8];    // [kseg][col][8]
    __shared__ int lidx[MROWS];

    const int t    = threadIdx.x;
    const int lane = t & 63;
    const int w    = t >> 6;
    const int m0   = (w % MW) * 64;
    const int n0   = (w / MW) * 64;
    const int base = blockIdx.x * MROWS;
    const int ar   = t % MROWS;          // A row this thread stages
    const int aks0 = t / MROWS;

    f32x4 acc[4][4];
    #pragma unroll
    for (int i = 0; i < 4; ++i)
        #pragma unroll
        for (int j = 0; j < 4; ++j)
            acc[i][j] = {0.f, 0.f, 0.f, 0.f};

    const bf16x8* lAv = (const bf16x8*)lA;
    const bf16x8* lBv = (const bf16x8*)lB;

    for (int koff = 0; koff < NOFF; ++koff) {
        __syncthreads();
        if (t < MROWS) {
            int p = base + t;
            int idx = -1;
            if (p < NPTS) idx = (koff == 27) ? p : nbr[(long)p * 27 + koff];
            lidx[t] = idx;
        }
        __syncthreads();
        const int myidx = lidx[ar];
        const bf16* row1 = (myidx >= 0) ? (F + (long)myidx * 448) : zrow;
        const bf16* row2 = row1;
        if constexpr (GATE == 2)
            row2 = (myidx >= 0) ? (f2 + (long)myidx * 128) : zrow;

        for (int ch = 0; ch < CHUNKS; ++ch) {
            const bf16* asrc = (GATE == 2 && ch < 2) ? (row2 + ch * 64)
                                                     : (row1 + ch * 64);
            #pragma unroll
            for (int p = 0; p < AP; ++p) {
                int kseg = aks0 + p * (THREADS / MROWS);
                __builtin_amdgcn_global_load_lds(
                    (void*)(asrc + kseg * 8),
                    (void*)(lA + ((long)t + (long)p * THREADS) * 8),
                    16, 0, 0);
            }
            const bf16* bsrc = WB + (long)(koff * CHUNKS + ch) * (NCOLS * 64);
            #pragma unroll
            for (int p = 0; p < BP; ++p) {
                __builtin_amdgcn_global_load_lds(
                    (void*)(bsrc + ((long)t + (long)p * THREADS) * 8),
                    (void*)(lB + ((long)t + (long)p * THREADS) * 8),
                    16, 0, 0);
            }
            __syncthreads();
            #pragma unroll
            for (int kk = 0; kk < 2; ++kk) {
                const int aseg = kk * 4 + (lane >> 4);
                bf16x8 af[4], bfr[4];
                #pragma unroll
                for (int mi = 0; mi < 4; ++mi)
                    af[mi] = lAv[aseg * MROWS + m0 + mi * 16 + (lane & 15)];
                #pragma unroll
                for (int ni = 0; ni < 4; ++ni)
                    bfr[ni] = lBv[aseg * NCOLS + n0 + ni * 16 + (lane & 15)];
                #pragma unroll
                for (int mi = 0; mi < 4; ++mi)
                    #pragma unroll
                    for (int ni = 0; ni < 4; ++ni)
                        acc[mi][ni] = __builtin_amdgcn_mfma_f32_16x16x32_bf16(
                            af[mi], bfr[ni], acc[mi][ni], 0, 0, 0);
            }
            __syncthreads();
        }
    }

    const int quad = lane >> 4;
    const int lc   = lane & 15;
    #pragma unroll
    for (int mi = 0; mi < 4; ++mi) {
        int rb = m0 + mi * 16 + quad * 4;
        #pragma unroll
        for (int ni = 0; ni < 4; ++ni) {
            int c = n0 + ni * 16 + lc;
            f32x4 v = acc[mi][ni];
            #pragma unroll
            for (int rg = 0; rg < 4; ++rg) {
                int p = base + rb + rg;
                if (p < NPTS) {
                    float pre = v[rg];
                    if constexpr (GATE == 1) {
                        if (c < 128) {
                            float z = 1.f / (1.f + __expf(-(pre + b0[c])));
                            zbuf[(long)p * 128 + c] = z;
                        } else {
                            int cc = c - 128;
                            float r = 1.f / (1.f + __expf(-(pre + b1[cc])));
                            f2[(long)p * 128 + cc] = (bf16)(r * hbuf[(long)p * 128 + cc]);
                        }
                    } else {
                        float q  = tanhf(pre + b0[c]);
                        float z  = zbuf[(long)p * 128 + c];
                        float hv = hbuf[(long)p * 128 + c];
                        out[(long)p * 128 + c] = (1.f - z) * hv + z * q;
                    }
                }
            }
        }
    }
}

extern "C" void kernel_launch(void* const* d_in, const int* in_sizes, int n_in,
                              void* d_out, int out_size, void* d_ws, size_t ws_size,
                              hipStream_t stream)
{
    const float* h   = (const float*)d_in[0];
    const float* x   = (const float*)d_in[1];
    const int*   nbr = (const int*)d_in[2];
    const float* Wz  = (const float*)d_in[3];
    const float* Wzp = (const float*)d_in[4];
    const float* bz  = (const float*)d_in[5];
    const float* Wr  = (const float*)d_in[6];
    const float* Wrp = (const float*)d_in[7];
    const float* br  = (const float*)d_in[8];
    const float* Wq  = (const float*)d_in[9];
    const float* Wqp = (const float*)d_in[10];
    const float* bq  = (const float*)d_in[11];
    float* out = (float*)d_out;

    char* ws = (char*)d_ws;
    bf16* WB1 = (bf16*)ws;  ws += (size_t)1568 * 256 * 8 * 2;   // 6.42 MB
    bf16* WB2 = (bf16*)ws;  ws += (size_t)1568 * 128 * 8 * 2;   // 3.21 MB
    bf16* F1  = (bf16*)ws;  ws += (size_t)NPTS * 448 * 2;       // 107.5 MB
    bf16* F2  = (bf16*)ws;  ws += (size_t)NPTS * 128 * 2;       // 30.7 MB  (r*h only)
    bf16* zrow = (bf16*)ws; ws += 1024;                          // zero row for masked gathers
    float* zbuf = out;  // z gate stored in d_out (fp32), overwritten by pass 2

    hipMemsetAsync(zrow, 0, 1024, stream);
    wprep1<<<1568, 256, 0, stream>>>(Wz, Wzp, Wr, Wrp, WB1);
    wprep2<<<1568, 128, 0, stream>>>(Wq, Wqp, WB2);
    long groups = (long)NPTS * 56;
    fprep<<<(int)((groups + 255) / 256), 256, 0, stream>>>(h, x, F1);

    gconv1p<<<(NPTS + 255) / 256, 512, 0, stream>>>(
        F1, nbr, WB1, bz, br, h, zbuf, F2, zrow);
    gconv<256, 128, 2><<<(NPTS + 255) / 256, 512, 0, stream>>>(
        F1, nbr, WB2, bq, nullptr, h, zbuf, F2, out, zrow);
}

// Round 3
// 1639.939 us; speedup vs baseline: 1.3836x; 1.0582x over previous
//
#include <hip/hip_runtime.h>

#define NPTS   120000
#define NOFF   28      // 27 neighbor offsets + 1 point-transform slot
#define CHUNKS 7       // 448 / 64

typedef __bf16 bf16;
typedef __bf16 bf16x8 __attribute__((ext_vector_type(8)));
typedef float  f32x4  __attribute__((ext_vector_type(4)));

// ---------------- weight prep: pack (Wz|Wr) -> WB1 [koff][chunk][kseg][n(256)][8k] bf16
__global__ void wprep1(const float* __restrict__ Wz, const float* __restrict__ Wzp,
                       const float* __restrict__ Wr, const float* __restrict__ Wrp,
                       bf16* __restrict__ WB1)
{
    int bid  = blockIdx.x;          // 28*7*8 = 1568
    int koff = bid / 56;
    int rem  = bid % 56;
    int ch   = rem / 8;
    int kseg = rem % 8;
    int n    = threadIdx.x;         // 256
    int cinb = ch * 64 + kseg * 8;
    bf16x8 v;
    if (n < 128) {
        int col = n;
        #pragma unroll
        for (int j = 0; j < 8; ++j) {
            int cin = cinb + j;
            float w = (koff < 27) ? Wz[((long)koff * 448 + cin) * 128 + col]
                                  : Wzp[(long)cin * 128 + col];
            v[j] = (bf16)w;
        }
    } else {
        int col = n - 128;
        #pragma unroll
        for (int j = 0; j < 8; ++j) {
            int cin = cinb + j;
            float w = (koff < 27) ? Wr[((long)koff * 448 + cin) * 128 + col]
                                  : Wrp[(long)cin * 128 + col];
            v[j] = (bf16)w;
        }
    }
    *(bf16x8*)(WB1 + ((long)bid * 256 + n) * 8) = v;
}

// ---------------- weight prep: pack Wq -> WB2 [koff][chunk][kseg][n(128)][8k] bf16
__global__ void wprep2(const float* __restrict__ Wq, const float* __restrict__ Wqp,
                       bf16* __restrict__ WB2)
{
    int bid  = blockIdx.x;          // 1568
    int koff = bid / 56;
    int rem  = bid % 56;
    int ch   = rem / 8;
    int kseg = rem % 8;
    int n    = threadIdx.x;         // 128
    int cinb = ch * 64 + kseg * 8;
    bf16x8 v;
    #pragma unroll
    for (int j = 0; j < 8; ++j) {
        int cin = cinb + j;
        float w = (koff < 27) ? Wq[((long)koff * 448 + cin) * 128 + n]
                              : Wqp[(long)cin * 128 + n];
        v[j] = (bf16)w;
    }
    *(bf16x8*)(WB2 + ((long)bid * 128 + n) * 8) = v;
}

// ---------------- feature prep: F1 = bf16([h|x]), vectorized 8 cols/thread
__global__ void fprep(const float* __restrict__ h, const float* __restrict__ x,
                      bf16* __restrict__ F1)
{
    long g = (long)blockIdx.x * blockDim.x + threadIdx.x;
    if (g >= (long)NPTS * 56) return;       // 448/8 = 56 groups per row
    int p = (int)(g / 56);
    int c = (int)(g % 56) * 8;              // 128 divisible by 8 -> no h/x straddle
    const float* src = (c < 128) ? h + (long)p * 128 + c
                                 : x + (long)p * 320 + (c - 128);
    float4 a = ((const float4*)src)[0];
    float4 b = ((const float4*)src)[1];
    bf16x8 v;
    v[0] = (bf16)a.x; v[1] = (bf16)a.y; v[2] = (bf16)a.z; v[3] = (bf16)a.w;
    v[4] = (bf16)b.x; v[5] = (bf16)b.y; v[6] = (bf16)b.z; v[7] = (bf16)b.w;
    *(bf16x8*)(F1 + (long)p * 448 + c) = v;
}

// ---------------- gather-GEMM, MROWS x NCOLS tile, 512 threads (8 waves, 64x64 each)
// Round-0 drain structure (3 blocks/CU TLP), but A-gather is COALESCED at row
// granularity: each wave-instr stages 8 rows x 128B (8 lanes x 16B contiguous per row)
// -> 16 cache-line requests/instr instead of 64.  LDS A-tile is row-major [row][128B]
// with XOR swizzle (rule #21, both sides): stage lane u writes global kseg
// (u&7)^(row&7) at linear LDS unit u; read fetches row*128 + ((aseg^(lc&7))<<4).
// Fragment content is identical to the old k-major layout (xor cancels).
// GATE==1 (128x256): cols 0..127 -> z=sigmoid -> zbuf(fp32); cols 128..255 -> r=sigmoid,
//                    f2[p*128+cc] = bf16(r*h).
// GATE==2 (256x128): A chunks 0-1 read from f2 (r*h, 128-wide), chunks 2-6 from F (x part);
//                    q=tanh, out=(1-z)h+zq.
template<int MROWS, int NCOLS, int GATE>
__global__ __launch_bounds__(512)
void gconv(const bf16* __restrict__ F, const int* __restrict__ nbr,
           const bf16* __restrict__ WB, const float* __restrict__ b0,
           const float* __restrict__ b1, const float* __restrict__ hbuf,
           float* __restrict__ zbuf, bf16* __restrict__ f2,
           float* __restrict__ out, const bf16* __restrict__ zrow)
{
    constexpr int THREADS = 512;
    constexpr int MW = MROWS / 64;              // m-waves
    constexpr int AP = 8 * MROWS / THREADS;     // A-tile 16B units per thread
    constexpr int BP = 8 * NCOLS / THREADS;     // B-tile 16B units per thread

    __shared__ __align__(16) bf16 lA[MROWS * 64];       // row-major [row][64k], XOR-swizzled
    __shared__ __align__(16) bf16 lB[8 * NCOLS * 8];    // k-major [kseg][col][8]
    __shared__ int lidx[MROWS];

    const int t    = threadIdx.x;
    const int lane = t & 63;
    const int w    = t >> 6;
    const int m0   = (w % MW) * 64;
    const int n0   = (w / MW) * 64;
    const int base = blockIdx.x * MROWS;
    // A staging: unit u = t + p*512 covers (row = u>>3, slot = u&7);
    // global kseg for this unit is slot ^ (row&7) -> constant per thread:
    const int ksegT = (t & 7) ^ ((t >> 3) & 7);

    f32x4 acc[4][4];
    #pragma unroll
    for (int i = 0; i < 4; ++i)
        #pragma unroll
        for (int j = 0; j < 4; ++j)
            acc[i][j] = {0.f, 0.f, 0.f, 0.f};

    const bf16x8* lBv = (const bf16x8*)lB;
    const int lc = lane & 15;
    const int q4 = lane >> 4;
    const int rx = lc & 7;          // == row&7 for every row this lane reads

    for (int koff = 0; koff < NOFF; ++koff) {
        __syncthreads();
        if (t < MROWS) {
            int p = base + t;
            int idx = -1;
            if (p < NPTS) idx = (koff == 27) ? p : nbr[(long)p * 27 + koff];
            lidx[t] = idx;
        }
        __syncthreads();
        // gather indices for the AP rows this thread stages (rows t>>3 + p*64)
        int ridx[AP];
        #pragma unroll
        for (int p = 0; p < AP; ++p)
            ridx[p] = lidx[(t >> 3) + p * (THREADS / 8)];

        for (int ch = 0; ch < CHUNKS; ++ch) {
            // stage A tile: 8 lanes cover one row's 128B chunk (coalesced gather)
            #pragma unroll
            for (int p = 0; p < AP; ++p) {
                int idx = ridx[p];
                const bf16* rp;
                if constexpr (GATE == 2) {
                    rp = (idx < 0) ? zrow
                       : (ch < 2)  ? f2 + (long)idx * 128 + ch * 64
                                   : F  + (long)idx * 448 + ch * 64;
                } else {
                    rp = (idx < 0) ? zrow : F + (long)idx * 448 + ch * 64;
                }
                __builtin_amdgcn_global_load_lds(
                    (void*)(rp + ksegT * 8),
                    (void*)(lA + ((long)t + (long)p * THREADS) * 8),
                    16, 0, 0);
            }
            // stage B tile (64k x NCOLS) -- contiguous packed weights
            const bf16* bsrc = WB + (long)(koff * CHUNKS + ch) * (NCOLS * 64);
            #pragma unroll
            for (int p = 0; p < BP; ++p) {
                __builtin_amdgcn_global_load_lds(
                    (void*)(bsrc + ((long)t + (long)p * THREADS) * 8),
                    (void*)(lB + ((long)t + (long)p * THREADS) * 8),
                    16, 0, 0);
            }
            __syncthreads();
            #pragma unroll
            for (int kk = 0; kk < 2; ++kk) {
                const int aseg = kk * 4 + q4;
                const int asl  = (aseg ^ rx) << 3;   // swizzled k-slot (bf16 elems)
                bf16x8 af[4], bfr[4];
                #pragma unroll
                for (int mi = 0; mi < 4; ++mi)
                    af[mi] = *(const bf16x8*)(lA + ((m0 + mi * 16 + lc) << 6) + asl);
                #pragma unroll
                for (int ni = 0; ni < 4; ++ni)
                    bfr[ni] = lBv[aseg * NCOLS + n0 + ni * 16 + lc];
                #pragma unroll
                for (int mi = 0; mi < 4; ++mi)
                    #pragma unroll
                    for (int ni = 0; ni < 4; ++ni)
                        acc[mi][ni] = __builtin_amdgcn_mfma_f32_16x16x32_bf16(
                            af[mi], bfr[ni], acc[mi][ni], 0, 0, 0);
            }
            __syncthreads();
        }
    }

    // epilogue: C/D layout col=lane&15, row=(lane>>4)*4+reg  [m89/m91]
    #pragma unroll
    for (int mi = 0; mi < 4; ++mi) {
        int rb = m0 + mi * 16 + q4 * 4;
        #pragma unroll
        for (int ni = 0; ni < 4; ++ni) {
            int c = n0 + ni * 16 + lc;
            f32x4 v = acc[mi][ni];
            #pragma unroll
            for (int rg = 0; rg < 4; ++rg) {
                int p = base + rb + rg;
                if (p < NPTS) {
                    float pre = v[rg];
                    if constexpr (GATE == 1) {
                        if (c < 128) {
                            float z = 1.f / (1.f + __expf(-(pre + b0[c])));
                            zbuf[(long)p * 128 + c] = z;
                        } else {
                            int cc = c - 128;
                            float r = 1.f / (1.f + __expf(-(pre + b1[cc])));
                            f2[(long)p * 128 + cc] = (bf16)(r * hbuf[(long)p * 128 + cc]);
                        }
                    } else {
                        float q  = tanhf(pre + b0[c]);
                        float z  = zbuf[(long)p * 128 + c];
                        float hv = hbuf[(long)p * 128 + c];
                        out[(long)p * 128 + c] = (1.f - z) * hv + z * q;
                    }
                }
            }
        }
    }
}

extern "C" void kernel_launch(void* const* d_in, const int* in_sizes, int n_in,
                              void* d_out, int out_size, void* d_ws, size_t ws_size,
                              hipStream_t stream)
{
    const float* h   = (const float*)d_in[0];
    const float* x   = (const float*)d_in[1];
    const int*   nbr = (const int*)d_in[2];
    const float* Wz  = (const float*)d_in[3];
    const float* Wzp = (const float*)d_in[4];
    const float* bz  = (const float*)d_in[5];
    const float* Wr  = (const float*)d_in[6];
    const float* Wrp = (const float*)d_in[7];
    const float* br  = (const float*)d_in[8];
    const float* Wq  = (const float*)d_in[9];
    const float* Wqp = (const float*)d_in[10];
    const float* bq  = (const float*)d_in[11];
    float* out = (float*)d_out;

    char* ws = (char*)d_ws;
    bf16* WB1 = (bf16*)ws;  ws += (size_t)1568 * 256 * 8 * 2;   // 6.42 MB
    bf16* WB2 = (bf16*)ws;  ws += (size_t)1568 * 128 * 8 * 2;   // 3.21 MB
    bf16* F1  = (bf16*)ws;  ws += (size_t)NPTS * 448 * 2;       // 107.5 MB
    bf16* F2  = (bf16*)ws;  ws += (size_t)NPTS * 128 * 2;       // 30.7 MB  (r*h only)
    bf16* zrow = (bf16*)ws; ws += 1024;                          // zero row for masked gathers
    float* zbuf = out;  // z gate stored in d_out (fp32), overwritten by pass 2

    hipMemsetAsync(zrow, 0, 1024, stream);
    wprep1<<<1568, 256, 0, stream>>>(Wz, Wzp, Wr, Wrp, WB1);
    wprep2<<<1568, 128, 0, stream>>>(Wq, Wqp, WB2);
    long groups = (long)NPTS * 56;
    fprep<<<(int)((groups + 255) / 256), 256, 0, stream>>>(h, x, F1);

    gconv<128, 256, 1><<<(NPTS + 127) / 128, 512, 0, stream>>>(
        F1, nbr, WB1, bz, br, h, zbuf, F2, nullptr, zrow);
    gconv<256, 128, 2><<<(NPTS + 255) / 256, 512, 0, stream>>>(
        F1, nbr, WB2, bq, nullptr, h, zbuf, F2, out, zrow);
}

// Round 4
// 1554.870 us; speedup vs baseline: 1.4593x; 1.0547x over previous
//
#include <hip/hip_runtime.h>

#define NPTS   120000
#define NOFF   28      // 27 neighbor offsets + 1 point-transform slot
#define CHUNKS 7       // 448 / 64

typedef __bf16 bf16;
typedef __bf16 bf16x8 __attribute__((ext_vector_type(8)));
typedef float  f32x4  __attribute__((ext_vector_type(4)));

// ---------------- weight prep: pack (Wz|Wr) -> WB1 [koff][chunk][kseg][n(256)][8k] bf16
__global__ void wprep1(const float* __restrict__ Wz, const float* __restrict__ Wzp,
                       const float* __restrict__ Wr, const float* __restrict__ Wrp,
                       bf16* __restrict__ WB1)
{
    int bid  = blockIdx.x;          // 28*7*8 = 1568
    int koff = bid / 56;
    int rem  = bid % 56;
    int ch   = rem / 8;
    int kseg = rem % 8;
    int n    = threadIdx.x;         // 256
    int cinb = ch * 64 + kseg * 8;
    bf16x8 v;
    if (n < 128) {
        int col = n;
        #pragma unroll
        for (int j = 0; j < 8; ++j) {
            int cin = cinb + j;
            float w = (koff < 27) ? Wz[((long)koff * 448 + cin) * 128 + col]
                                  : Wzp[(long)cin * 128 + col];
            v[j] = (bf16)w;
        }
    } else {
        int col = n - 128;
        #pragma unroll
        for (int j = 0; j < 8; ++j) {
            int cin = cinb + j;
            float w = (koff < 27) ? Wr[((long)koff * 448 + cin) * 128 + col]
                                  : Wrp[(long)cin * 128 + col];
            v[j] = (bf16)w;
        }
    }
    *(bf16x8*)(WB1 + ((long)bid * 256 + n) * 8) = v;
}

// ---------------- weight prep: pack Wq -> WB2 [koff][chunk][kseg][n(128)][8k] bf16
__global__ void wprep2(const float* __restrict__ Wq, const float* __restrict__ Wqp,
                       bf16* __restrict__ WB2)
{
    int bid  = blockIdx.x;          // 1568
    int koff = bid / 56;
    int rem  = bid % 56;
    int ch   = rem / 8;
    int kseg = rem % 8;
    int n    = threadIdx.x;         // 128
    int cinb = ch * 64 + kseg * 8;
    bf16x8 v;
    #pragma unroll
    for (int j = 0; j < 8; ++j) {
        int cin = cinb + j;
        float w = (koff < 27) ? Wq[((long)koff * 448 + cin) * 128 + n]
                              : Wqp[(long)cin * 128 + n];
        v[j] = (bf16)w;
    }
    *(bf16x8*)(WB2 + ((long)bid * 128 + n) * 8) = v;
}

// ---------------- feature prep: F1 = bf16([h|x]), vectorized 8 cols/thread
__global__ void fprep(const float* __restrict__ h, const float* __restrict__ x,
                      bf16* __restrict__ F1)
{
    long g = (long)blockIdx.x * blockDim.x + threadIdx.x;
    if (g >= (long)NPTS * 56) return;       // 448/8 = 56 groups per row
    int p = (int)(g / 56);
    int c = (int)(g % 56) * 8;              // 128 divisible by 8 -> no h/x straddle
    const float* src = (c < 128) ? h + (long)p * 128 + c
                                 : x + (long)p * 320 + (c - 128);
    float4 a = ((const float4*)src)[0];
    float4 b = ((const float4*)src)[1];
    bf16x8 v;
    v[0] = (bf16)a.x; v[1] = (bf16)a.y; v[2] = (bf16)a.z; v[3] = (bf16)a.w;
    v[4] = (bf16)b.x; v[5] = (bf16)b.y; v[6] = (bf16)b.z; v[7] = (bf16)b.w;
    *(bf16x8*)(F1 + (long)p * 448 + c) = v;
}

// T1: bijective XCD swizzle (m204) -- consecutive logical blocks land on the same XCD,
// so neighboring point-tiles (which share gather rows, points are cell-sorted) share L2.
__device__ __forceinline__ int xcd_swizzle(int orig, int nwg)
{
    int xcd = orig & 7;
    int i   = orig >> 3;
    int q   = nwg >> 3;
    int r   = nwg & 7;
    return (xcd < r ? xcd * (q + 1) : r * (q + 1) + (xcd - r) * q) + i;
}

// ---------------- gather-GEMM, MROWS x NCOLS tile, THREADS threads (64x64 per wave)
// Drain structure (TLP-based hiding), coalesced row-grouped A-gather: each wave-instr
// stages 8 rows x 128B (8 lanes x 16B contiguous per row).  LDS A-tile row-major
// [row][64k] with XOR swizzle (rule #21, both sides): stage unit u writes global kseg
// (u&7)^((u>>3)&7) at linear LDS unit u; read fetches row*128B + ((aseg^(lc&7))<<4).
// Fragment content identical to k-major layout (xor cancels); measured 0 bank conflicts.
// GATE==1 (128x256, 512 thr): cols 0..127 -> z=sigmoid -> zbuf; cols 128..255 -> r,
//                    f2 = bf16(r*h).
// GATE==2 (128x128, 256 thr): A chunks 0-1 from f2 (r*h), 2-6 from F; q=tanh,
//                    out=(1-z)h+zq.  128-row shape transplanted from proven GATE==1.
template<int MROWS, int NCOLS, int GATE, int THREADS>
__global__ __launch_bounds__(THREADS)
void gconv(const bf16* __restrict__ F, const int* __restrict__ nbr,
           const bf16* __restrict__ WB, const float* __restrict__ b0,
           const float* __restrict__ b1, const float* __restrict__ hbuf,
           float* __restrict__ zbuf, bf16* __restrict__ f2,
           float* __restrict__ out, const bf16* __restrict__ zrow)
{
    constexpr int MW = MROWS / 64;              // m-waves
    constexpr int AP = 8 * MROWS / THREADS;     // A-tile 16B units per thread
    constexpr int BP = 8 * NCOLS / THREADS;     // B-tile 16B units per thread
    static_assert((THREADS / 8) % 8 == 0, "row-group stride must preserve row&7");

    __shared__ __align__(16) bf16 lA[MROWS * 64];       // row-major [row][64k], XOR-swizzled
    __shared__ __align__(16) bf16 lB[8 * NCOLS * 8];    // k-major [kseg][col][8]
    __shared__ int lidx[MROWS];

    const int t    = threadIdx.x;
    const int lane = t & 63;
    const int w    = t >> 6;
    const int m0   = (w % MW) * 64;
    const int n0   = (w / MW) * 64;
    const int bid  = xcd_swizzle(blockIdx.x, gridDim.x);
    const int base = bid * MROWS;
    // A staging: unit u = t + p*THREADS covers (row = u>>3, slot = u&7);
    // global kseg for this unit is slot ^ (row&7) -> constant per thread:
    const int ksegT = (t & 7) ^ ((t >> 3) & 7);

    f32x4 acc[4][4];
    #pragma unroll
    for (int i = 0; i < 4; ++i)
        #pragma unroll
        for (int j = 0; j < 4; ++j)
            acc[i][j] = {0.f, 0.f, 0.f, 0.f};

    const bf16x8* lBv = (const bf16x8*)lB;
    const int lc = lane & 15;
    const int q4 = lane >> 4;
    const int rx = lc & 7;          // == row&7 for every row this lane reads

    for (int koff = 0; koff < NOFF; ++koff) {
        __syncthreads();
        if (t < MROWS) {
            int p = base + t;
            int idx = -1;
            if (p < NPTS) idx = (koff == 27) ? p : nbr[(long)p * 27 + koff];
            lidx[t] = idx;
        }
        __syncthreads();
        // gather indices for the AP rows this thread stages (rows t>>3 + p*(THREADS/8))
        int ridx[AP];
        #pragma unroll
        for (int p = 0; p < AP; ++p)
            ridx[p] = lidx[(t >> 3) + p * (THREADS / 8)];

        for (int ch = 0; ch < CHUNKS; ++ch) {
            // stage A tile: 8 lanes cover one row's 128B chunk (coalesced gather)
            #pragma unroll
            for (int p = 0; p < AP; ++p) {
                int idx = ridx[p];
                const bf16* rp;
                if constexpr (GATE == 2) {
                    rp = (idx < 0) ? zrow
                       : (ch < 2)  ? f2 + (long)idx * 128 + ch * 64
                                   : F  + (long)idx * 448 + ch * 64;
                } else {
                    rp = (idx < 0) ? zrow : F + (long)idx * 448 + ch * 64;
                }
                __builtin_amdgcn_global_load_lds(
                    (void*)(rp + ksegT * 8),
                    (void*)(lA + ((long)t + (long)p * THREADS) * 8),
                    16, 0, 0);
            }
            // stage B tile (64k x NCOLS) -- contiguous packed weights
            const bf16* bsrc = WB + (long)(koff * CHUNKS + ch) * (NCOLS * 64);
            #pragma unroll
            for (int p = 0; p < BP; ++p) {
                __builtin_amdgcn_global_load_lds(
                    (void*)(bsrc + ((long)t + (long)p * THREADS) * 8),
                    (void*)(lB + ((long)t + (long)p * THREADS) * 8),
                    16, 0, 0);
            }
            __syncthreads();
            #pragma unroll
            for (int kk = 0; kk < 2; ++kk) {
                const int aseg = kk * 4 + q4;
                const int asl  = (aseg ^ rx) << 3;   // swizzled k-slot (bf16 elems)
                bf16x8 af[4], bfr[4];
                #pragma unroll
                for (int mi = 0; mi < 4; ++mi)
                    af[mi] = *(const bf16x8*)(lA + ((m0 + mi * 16 + lc) << 6) + asl);
                #pragma unroll
                for (int ni = 0; ni < 4; ++ni)
                    bfr[ni] = lBv[aseg * NCOLS + n0 + ni * 16 + lc];
                #pragma unroll
                for (int mi = 0; mi < 4; ++mi)
                    #pragma unroll
                    for (int ni = 0; ni < 4; ++ni)
                        acc[mi][ni] = __builtin_amdgcn_mfma_f32_16x16x32_bf16(
                            af[mi], bfr[ni], acc[mi][ni], 0, 0, 0);
            }
            __syncthreads();
        }
    }

    // epilogue: C/D layout col=lane&15, row=(lane>>4)*4+reg  [m89/m91]
    #pragma unroll
    for (int mi = 0; mi < 4; ++mi) {
        int rb = m0 + mi * 16 + q4 * 4;
        #pragma unroll
        for (int ni = 0; ni < 4; ++ni) {
            int c = n0 + ni * 16 + lc;
            f32x4 v = acc[mi][ni];
            #pragma unroll
            for (int rg = 0; rg < 4; ++rg) {
                int p = base + rb + rg;
                if (p < NPTS) {
                    float pre = v[rg];
                    if constexpr (GATE == 1) {
                        if (c < 128) {
                            float z = 1.f / (1.f + __expf(-(pre + b0[c])));
                            zbuf[(long)p * 128 + c] = z;
                        } else {
                            int cc = c - 128;
                            float r = 1.f / (1.f + __expf(-(pre + b1[cc])));
                            f2[(long)p * 128 + cc] = (bf16)(r * hbuf[(long)p * 128 + cc]);
                        }
                    } else {
                        float q  = tanhf(pre + b0[c]);
                        float z  = zbuf[(long)p * 128 + c];
                        float hv = hbuf[(long)p * 128 + c];
                        out[(long)p * 128 + c] = (1.f - z) * hv + z * q;
                    }
                }
            }
        }
    }
}

extern "C" void kernel_launch(void* const* d_in, const int* in_sizes, int n_in,
                              void* d_out, int out_size, void* d_ws, size_t ws_size,
                              hipStream_t stream)
{
    const float* h   = (const float*)d_in[0];
    const float* x   = (const float*)d_in[1];
    const int*   nbr = (const int*)d_in[2];
    const float* Wz  = (const float*)d_in[3];
    const float* Wzp = (const float*)d_in[4];
    const float* bz  = (const float*)d_in[5];
    const float* Wr  = (const float*)d_in[6];
    const float* Wrp = (const float*)d_in[7];
    const float* br  = (const float*)d_in[8];
    const float* Wq  = (const float*)d_in[9];
    const float* Wqp = (const float*)d_in[10];
    const float* bq  = (const float*)d_in[11];
    float* out = (float*)d_out;

    char* ws = (char*)d_ws;
    bf16* WB1 = (bf16*)ws;  ws += (size_t)1568 * 256 * 8 * 2;   // 6.42 MB
    bf16* WB2 = (bf16*)ws;  ws += (size_t)1568 * 128 * 8 * 2;   // 3.21 MB
    bf16* F1  = (bf16*)ws;  ws += (size_t)NPTS * 448 * 2;       // 107.5 MB
    bf16* F2  = (bf16*)ws;  ws += (size_t)NPTS * 128 * 2;       // 30.7 MB  (r*h only)
    bf16* zrow = (bf16*)ws; ws += 1024;                          // zero row for masked gathers
    float* zbuf = out;  // z gate stored in d_out (fp32), overwritten by pass 2

    hipMemsetAsync(zrow, 0, 1024, stream);
    wprep1<<<1568, 256, 0, stream>>>(Wz, Wzp, Wr, Wrp, WB1);
    wprep2<<<1568, 128, 0, stream>>>(Wq, Wqp, WB2);
    long groups = (long)NPTS * 56;
    fprep<<<(int)((groups + 255) / 256), 256, 0, stream>>>(h, x, F1);

    gconv<128, 256, 1, 512><<<(NPTS + 127) / 128, 512, 0, stream>>>(
        F1, nbr, WB1, bz, br, h, zbuf, F2, nullptr, zrow);
    gconv<128, 128, 2, 256><<<(NPTS + 127) / 128, 256, 0, stream>>>(
        F1, nbr, WB2, bq, nullptr, h, zbuf, F2, out, zrow);
}